// Round 2
// baseline (1424.469 us; speedup 1.0000x reference)
//
#include <hip/hip_runtime.h>
#include <cstddef>

// Problem dims
#define DN 192
#define DM 256
#define DD 1024
#define DK 65
#define OUTW 192   // DM - DK + 1

#define CB 16      // scan steps per d-block
#define NB 64      // number of d-blocks (CB*NB = 1024 = D, slice 1023 is h0)
#define R1 24      // rows per workgroup, phase 1
#define RB1 8      // 192 / 24
#define PSTR 260   // padded LDS row stride (floats) -> bank-conflict-free

// ws layout (float offsets)
#define OFF_W0T 0u
#define OFF_W1T 65536u
#define OFF_PW  131072u                   // 4 slots used: Q^2,Q^4,Q^8,Q^16
#define OFF_S   (131072u + 5u*65536u)     // S_all[64][192][256] = 12.6 MB

__device__ __forceinline__ float sigm(float v) {
    return 1.0f / (1.0f + __expf(-v));
}

// Build m-major transposed weights: W0t[m][k] = W[k][m][0], W1t[m][k] = W[k][m][1]
__global__ __launch_bounds__(256) void k_prep(const float* __restrict__ W,
                                              float* __restrict__ ws) {
    const int m = blockIdx.x;   // 0..255
    const int k = threadIdx.x;  // 0..255
    const float2 w = *reinterpret_cast<const float2*>(W + (size_t)k * 512 + m * 2);
    ws[OFF_W0T + m * 256 + k] = w.x;
    ws[OFF_W1T + m * 256 + k] = w.y;
}

// C = A * A  (256x256 row-major fp32 matmul)
__global__ __launch_bounds__(256) void k_sq(const float* __restrict__ A,
                                            float* __restrict__ C) {
    __shared__ float ar[4][PSTR];
    const int r0 = blockIdx.x * 4;
    const int k  = threadIdx.x;
    for (int r = 0; r < 4; ++r) ar[r][k] = A[(r0 + r) * 256 + k];
    __syncthreads();
    float a0 = 0.f, a1 = 0.f, a2 = 0.f, a3 = 0.f;
    for (int m = 0; m < 256; m += 4) {
        const float p0 = A[(m + 0) * 256 + k];
        const float p1 = A[(m + 1) * 256 + k];
        const float p2 = A[(m + 2) * 256 + k];
        const float p3 = A[(m + 3) * 256 + k];
        float4 t;
        t = *reinterpret_cast<const float4*>(&ar[0][m]);
        a0 += t.x * p0 + t.y * p1 + t.z * p2 + t.w * p3;
        t = *reinterpret_cast<const float4*>(&ar[1][m]);
        a1 += t.x * p0 + t.y * p1 + t.z * p2 + t.w * p3;
        t = *reinterpret_cast<const float4*>(&ar[2][m]);
        a2 += t.x * p0 + t.y * p1 + t.z * p2 + t.w * p3;
        t = *reinterpret_cast<const float4*>(&ar[3][m]);
        a3 += t.x * p0 + t.y * p1 + t.z * p2 + t.w * p3;
    }
    C[(r0 + 0) * 256 + k] = a0;
    C[(r0 + 1) * 256 + k] = a1;
    C[(r0 + 2) * 256 + k] = a2;
    C[(r0 + 3) * 256 + k] = a3;
}

// Phase 1: per (row-block, d-block) local Horner:
//   S_b = sum_{d'=0}^{CB-1} v_{CB*b+d'} * Q^{d'},  v_d = u_d (d<=1022), v_1023 = h0
// u_d[i,k] = sum_m rows_d[i,m]*W0t[m,k] + b[k] + sigmoid(rows_d[i,k])
__global__ __launch_bounds__(256) void k_phase1(const float* __restrict__ NAT,
                                                const float* __restrict__ bvec,
                                                const float* __restrict__ ws,
                                                float* __restrict__ Sall) {
    __shared__ float Sl[R1 * PSTR];
    __shared__ float Rl[R1 * PSTR];
    const int rb  = blockIdx.x;   // 0..7
    const int bb  = blockIdx.y;   // 0..63
    const int tid = threadIdx.x;
    const int tj  = tid & 63;     // cols 4*tj .. 4*tj+3
    const int ti  = tid >> 6;     // rows ti*6 .. ti*6+5
    const int n0  = rb * R1;
    const float* __restrict__ W0t = ws + OFF_W0T;
    const float* __restrict__ W1t = ws + OFF_W1T;
    const float4 bv = *reinterpret_cast<const float4*>(bvec + 4 * tj);
    float acc[6][4];

    for (int it = 0; it < CB; ++it) {
        const int d = bb * CB + (CB - 1) - it;
        // stage slice d -> Rl (coalesced: 64 lanes x float4 per row)
#pragma unroll
        for (int q = 0; q < 6; ++q) {
            const int row = q * 4 + ti;
            const float4 v = *reinterpret_cast<const float4*>(
                NAT + ((size_t)(n0 + row) * DD + d) * DM + 4 * tj);
            *reinterpret_cast<float4*>(&Rl[row * PSTR + 4 * tj]) = v;
        }
        __syncthreads();

        if (d == DD - 1) {
            // v_1023 = h0: plain copy (S_old is zero here: it==0 of last block)
#pragma unroll
            for (int r = 0; r < 6; ++r) {
                const float4 v = *reinterpret_cast<const float4*>(
                    &Rl[(ti * 6 + r) * PSTR + 4 * tj]);
                acc[r][0] = v.x; acc[r][1] = v.y; acc[r][2] = v.z; acc[r][3] = v.w;
            }
        } else {
            // init with b + sigmoid(rows[i, j..j+3])
#pragma unroll
            for (int r = 0; r < 6; ++r) {
                const float4 v = *reinterpret_cast<const float4*>(
                    &Rl[(ti * 6 + r) * PSTR + 4 * tj]);
                acc[r][0] = bv.x + sigm(v.x);
                acc[r][1] = bv.y + sigm(v.y);
                acc[r][2] = bv.z + sigm(v.z);
                acc[r][3] = bv.w + sigm(v.w);
            }
            if (it == 0) {
                // first step of the block: S (old) is zero -> W0 part only
#pragma unroll 2
                for (int m = 0; m < DM; m += 2) {
                    const float4 w0a = *reinterpret_cast<const float4*>(W0t + m * DM + 4 * tj);
                    const float4 w0b = *reinterpret_cast<const float4*>(W0t + (m + 1) * DM + 4 * tj);
#pragma unroll
                    for (int r = 0; r < 6; ++r) {
                        const float2 rv = *reinterpret_cast<const float2*>(&Rl[(ti * 6 + r) * PSTR + m]);
                        acc[r][0] += rv.x * w0a.x + rv.y * w0b.x;
                        acc[r][1] += rv.x * w0a.y + rv.y * w0b.y;
                        acc[r][2] += rv.x * w0a.z + rv.y * w0b.z;
                        acc[r][3] += rv.x * w0a.w + rv.y * w0b.w;
                    }
                }
            } else {
#pragma unroll 2
                for (int m = 0; m < DM; m += 2) {
                    const float4 w0a = *reinterpret_cast<const float4*>(W0t + m * DM + 4 * tj);
                    const float4 w0b = *reinterpret_cast<const float4*>(W0t + (m + 1) * DM + 4 * tj);
                    const float4 w1a = *reinterpret_cast<const float4*>(W1t + m * DM + 4 * tj);
                    const float4 w1b = *reinterpret_cast<const float4*>(W1t + (m + 1) * DM + 4 * tj);
#pragma unroll
                    for (int r = 0; r < 6; ++r) {
                        const float2 rv = *reinterpret_cast<const float2*>(&Rl[(ti * 6 + r) * PSTR + m]);
                        const float2 sv = *reinterpret_cast<const float2*>(&Sl[(ti * 6 + r) * PSTR + m]);
                        acc[r][0] += rv.x * w0a.x + rv.y * w0b.x + sv.x * w1a.x + sv.y * w1b.x;
                        acc[r][1] += rv.x * w0a.y + rv.y * w0b.y + sv.x * w1a.y + sv.y * w1b.y;
                        acc[r][2] += rv.x * w0a.z + rv.y * w0b.z + sv.x * w1a.z + sv.y * w1b.z;
                        acc[r][3] += rv.x * w0a.w + rv.y * w0b.w + sv.x * w1a.w + sv.y * w1b.w;
                    }
                }
            }
        }
        __syncthreads();   // all reads of old Sl done
#pragma unroll
        for (int r = 0; r < 6; ++r) {
            float4 v;
            v.x = acc[r][0]; v.y = acc[r][1]; v.z = acc[r][2]; v.w = acc[r][3];
            *reinterpret_cast<float4*>(&Sl[(ti * 6 + r) * PSTR + 4 * tj]) = v;
        }
        __syncthreads();   // Sl update visible before next compute
    }

    // acc holds S_b for this row block
    float* dst = Sall + ((size_t)bb * DN + n0) * DM;
#pragma unroll
    for (int r = 0; r < 6; ++r) {
        float4 v;
        v.x = acc[r][0]; v.y = acc[r][1]; v.z = acc[r][2]; v.w = acc[r][3];
        *reinterpret_cast<float4*>(dst + (size_t)(ti * 6 + r) * DM + 4 * tj) = v;
    }
}

// Phase 2: per-row Horner over blocks: T = S_b + T*P  (b = NB-2..0, T init = S_{NB-1}),
// P = Q^CB. Then fused epilogue: relu(T + x) -> conv(W2) + b2 -> sigmoid -> out
__global__ __launch_bounds__(256) void k_phase2(const float* __restrict__ Sall,
                                                const float* __restrict__ P,
                                                const float* __restrict__ x,
                                                const float* __restrict__ W2,
                                                const float* __restrict__ b2p,
                                                float* __restrict__ out) {
    __shared__ float Tl[2][DM];
    __shared__ float resl[DM];
    const int n = blockIdx.x;    // 0..191
    const int k = threadIdx.x;   // 0..255

    float a = Sall[((size_t)(NB - 1) * DN + n) * DM + k];
    Tl[0][k] = a;
    __syncthreads();
    int cur = 0;

    for (int b = NB - 2; b >= 0; --b) {
        const float s0 = Sall[((size_t)b * DN + n) * DM + k];
        float acc0 = 0.f, acc1 = 0.f, acc2 = 0.f, acc3 = 0.f;
        for (int m = 0; m < DM; m += 8) {
            const float4 t0 = *reinterpret_cast<const float4*>(&Tl[cur][m]);
            const float4 t1 = *reinterpret_cast<const float4*>(&Tl[cur][m + 4]);
            acc0 += t0.x * P[(m + 0) * DM + k] + t1.x * P[(m + 4) * DM + k];
            acc1 += t0.y * P[(m + 1) * DM + k] + t1.y * P[(m + 5) * DM + k];
            acc2 += t0.z * P[(m + 2) * DM + k] + t1.z * P[(m + 6) * DM + k];
            acc3 += t0.w * P[(m + 3) * DM + k] + t1.w * P[(m + 7) * DM + k];
        }
        a = s0 + ((acc0 + acc1) + (acc2 + acc3));
        Tl[cur ^ 1][k] = a;
        __syncthreads();
        cur ^= 1;
    }

    // epilogue: res = relu(h_fin + x), conv, sigmoid
    float r = a + x[(size_t)n * DM + k];
    resl[k] = r > 0.f ? r : 0.f;
    __syncthreads();

    if (k < OUTW) {
        float o = *b2p;
#pragma unroll 5
        for (int i = 0; i < DK; ++i) o += resl[k + i] * W2[i];
        out[(size_t)n * OUTW + k] = sigm(o);
    }
}

extern "C" void kernel_launch(void* const* d_in, const int* in_sizes, int n_in,
                              void* d_out, int out_size, void* d_ws, size_t ws_size,
                              hipStream_t stream) {
    const float* NAT = (const float*)d_in[0];
    const float* W   = (const float*)d_in[1];
    const float* bv  = (const float*)d_in[2];
    const float* x   = (const float*)d_in[3];
    const float* W2  = (const float*)d_in[4];
    const float* b2  = (const float*)d_in[5];
    float* out = (float*)d_out;
    float* ws  = (float*)d_ws;

    // m-major transposed weights (also Q = W1^T for the power chain)
    k_prep<<<256, 256, 0, stream>>>(W, ws);

    // P = Q^16 via 4 squarings
    const float* q = ws + OFF_W1T;
    float* pw = ws + OFF_PW;
    k_sq<<<64, 256, 0, stream>>>(q,              pw + 0 * 65536);
    k_sq<<<64, 256, 0, stream>>>(pw + 0 * 65536, pw + 1 * 65536);
    k_sq<<<64, 256, 0, stream>>>(pw + 1 * 65536, pw + 2 * 65536);
    k_sq<<<64, 256, 0, stream>>>(pw + 2 * 65536, pw + 3 * 65536);

    float* Sall = ws + OFF_S;
    k_phase1<<<dim3(RB1, NB), 256, 0, stream>>>(NAT, bv, ws, Sall);
    k_phase2<<<192, 256, 0, stream>>>(Sall, pw + 3 * 65536, x, W2, b2, out);
}

// Round 4
// 456.339 us; speedup vs baseline: 3.1215x; 3.1215x over previous
//
#include <hip/hip_runtime.h>
#include <hip/hip_bf16.h>
#include <cstddef>

// Problem dims
#define DN 192
#define DM 256
#define DD 1024
#define DK 65
#define OUTW 192

using f32x4 = __attribute__((ext_vector_type(4))) float;
using s16x8 = __attribute__((ext_vector_type(8))) short;

__device__ __forceinline__ float sigm(float v) { return 1.0f / (1.0f + __expf(-v)); }
__device__ __forceinline__ unsigned short f2b(float f) {
    __hip_bfloat16 h = __float2bfloat16(f);
    return *reinterpret_cast<unsigned short*>(&h);
}
__device__ __forceinline__ float b2f(unsigned short s) {
    __hip_bfloat16 h = *reinterpret_cast<__hip_bfloat16*>(&s);
    return __bfloat162float(h);
}

// ---------------- MFMA path ws layout (float offsets) ----------------
// Q^1..Q^64 fp32 chain (7 x 65536), then bf16 B-frag tables (4 x 32768),
// then SA1 (bf16, 128 groups), SA2 (f32, 16 groups), then Vc (bf16).
#define OFF_QF   0u
#define OFF_A2   65536u
#define OFF_A4   131072u
#define OFF_A8   196608u
#define OFF_A16  262144u
#define OFF_A32  327680u
#define OFF_A64  393216u
#define OFF_QB   458752u
#define OFF_W0B  491520u
#define OFF_P8B  524288u
#define OFF_P64B 557056u
#define OFF_SA1  589824u      // bf16 [128][192][256] C-frag = 3145728 f
#define OFF_SA2  3735552u     // f32  [16][192][256] C-frag  = 786432 f
#define OFF_VC   4521984u     // bf16 C-frag V slices
#define TIER_A_BYTES 118751232ULL   // VC holds 1024 slices (25165824 f)
#define TIER_B_BYTES  30670848ULL   // VC holds 128 slices  (3145728 f)

// Build: Qf fp32 [m][c] = W[c][m][1]; QB/W0B bf16 B-frag lane tables.
// B-frag entry e=(ct,ks,lane): 8 bf16, value(j) = M[ks*32+(l>>4)*8+j][ct*16+(l&15)]
__global__ __launch_bounds__(256) void k_prep2(const float* __restrict__ W,
                                               float* __restrict__ ws) {
    const int bid = blockIdx.x, t = threadIdx.x;
    if (bid < 256) {
        const int c = bid, m = t;
        ws[OFF_QF + m * 256 + c] = W[(size_t)(c * 256 + m) * 2 + 1];
    } else {
        const int which = (bid - 256) >> 5;           // 0 -> QB, 1 -> W0B
        const int e = ((bid - 256) & 31) * 256 + t;   // 0..8191
        const int ct = e >> 9, ks = (e >> 6) & 7, l = e & 63;
        const int c = ct * 16 + (l & 15);
        const int mb = ks * 32 + (l >> 4) * 8;
        s16x8 pk;
#pragma unroll
        for (int j = 0; j < 8; ++j)
            pk[j] = (short)f2b(W[(size_t)(c * 256 + mb + j) * 2 + (which ? 0 : 1)]);
        float* dst = ws + (which ? OFF_W0B : OFF_QB);
        reinterpret_cast<s16x8*>(dst)[e] = pk;
    }
}

// C = A*A (fp32 256x256, plain [m][c] layout). One output row per WG.
// If bfrag != null, also emit C's bf16 B-frag table entries for row r0.
__global__ __launch_bounds__(256) void k_sq256(const float* __restrict__ A,
                                               float* __restrict__ C,
                                               ushort* __restrict__ bfrag) {
    __shared__ float ar[256];
    const int r0 = blockIdx.x, k = threadIdx.x;
    ar[k] = A[r0 * 256 + k];
    __syncthreads();
    float a0 = 0.f, a1 = 0.f, a2 = 0.f, a3 = 0.f;
    for (int m = 0; m < 256; m += 8) {
        a0 += ar[m + 0] * A[(m + 0) * 256 + k] + ar[m + 4] * A[(m + 4) * 256 + k];
        a1 += ar[m + 1] * A[(m + 1) * 256 + k] + ar[m + 5] * A[(m + 5) * 256 + k];
        a2 += ar[m + 2] * A[(m + 2) * 256 + k] + ar[m + 6] * A[(m + 6) * 256 + k];
        a3 += ar[m + 3] * A[(m + 3) * 256 + k] + ar[m + 7] * A[(m + 7) * 256 + k];
    }
    const float v = (a0 + a1) + (a2 + a3);
    C[r0 * 256 + k] = v;
    if (bfrag) {
        // row r0 of C -> B-frag coords: ks=r0>>5, g=(r0>>3)&3, j=r0&7; col k -> ct=k>>4, l&15=k&15
        const int entry = ((k >> 4) * 8 + (r0 >> 5)) * 64 + ((r0 >> 3) & 3) * 16 + (k & 15);
        bfrag[entry * 8 + (r0 & 7)] = f2b(v);
    }
}

// Phase 1a: V_d = R_d*W0^T + b + sigma(R_d) for nd slices starting at d0_base.
// Grid (12 row-tiles of 16, nd/4). 512 thr = 8 waves; wave owns 32 cols.
// Output Vc bf16 C-frag [d_local][rt(12)][ct(16)][lane(64)][4]
__global__ __launch_bounds__(512) void k_phase1a(const float* __restrict__ NAT,
                                                 const float* __restrict__ bvec,
                                                 const float* __restrict__ ws,
                                                 unsigned short* __restrict__ Vc,
                                                 int d0_base) {
    __shared__ short Rl[4][8][65][8];   // [dd][ks][slot(+pad)][8 bf16]
    const int rt = blockIdx.x;          // 0..11
    const int dq = blockIdx.y;          // local quad
    const int n0 = rt * 16;
    const int tid = threadIdx.x;
    const int w = tid >> 6, l = tid & 63;
    const ushort* W0b = reinterpret_cast<const ushort*>(ws + OFF_W0B);

    // stage 16 rows x 4 d x 256 m -> bf16 A-frag layout
    {
        const int r = (tid >> 3) & 15, dd = tid >> 7, ks = tid & 7;
        const int dg = d0_base + dq * 4 + dd;
        const float* src = NAT + ((size_t)(n0 + r) * DD + dg) * DM + ks * 32;
        float f[32];
#pragma unroll
        for (int q = 0; q < 8; ++q) {
            const float4 v4 = *reinterpret_cast<const float4*>(src + q * 4);
            f[q * 4 + 0] = v4.x; f[q * 4 + 1] = v4.y; f[q * 4 + 2] = v4.z; f[q * 4 + 3] = v4.w;
        }
#pragma unroll
        for (int g = 0; g < 4; ++g) {
            s16x8 pk;
#pragma unroll
            for (int j = 0; j < 8; ++j) pk[j] = (short)f2b(f[g * 8 + j]);
            *reinterpret_cast<s16x8*>(&Rl[dd][ks][r + 16 * g][0]) = pk;
        }
    }
    __syncthreads();

    // acc init: b[col] + sigmoid(R[row, d, col])
    f32x4 acc[4][2];
    float bcol[2];
#pragma unroll
    for (int c = 0; c < 2; ++c) bcol[c] = bvec[w * 32 + c * 16 + (l & 15)];
#pragma unroll
    for (int dd = 0; dd < 4; ++dd)
#pragma unroll
        for (int c = 0; c < 2; ++c) {
            const int col = w * 32 + c * 16 + (l & 15);
            const int ksm = col >> 5, sl = 16 * ((col >> 3) & 3), jb = col & 7;
#pragma unroll
            for (int r = 0; r < 4; ++r) {
                const int row15 = (l >> 4) * 4 + r;
                unsigned short sv = (unsigned short)Rl[dd][ksm][row15 + sl][jb];
                acc[dd][c][r] = bcol[c] + sigm(b2f(sv));
            }
        }

    // acc += R * W0^T  (B-frags streamed from L2)
    for (int ks = 0; ks < 8; ++ks) {
        const s16x8 gb0 = *reinterpret_cast<const s16x8*>(W0b + (((2 * w + 0) * 8 + ks) * 64 + l) * 8);
        const s16x8 gb1 = *reinterpret_cast<const s16x8*>(W0b + (((2 * w + 1) * 8 + ks) * 64 + l) * 8);
#pragma unroll
        for (int dd = 0; dd < 4; ++dd) {
            const s16x8 a = *reinterpret_cast<const s16x8*>(&Rl[dd][ks][l][0]);
            acc[dd][0] = __builtin_amdgcn_mfma_f32_16x16x32_bf16(a, gb0, acc[dd][0], 0, 0, 0);
            acc[dd][1] = __builtin_amdgcn_mfma_f32_16x16x32_bf16(a, gb1, acc[dd][1], 0, 0, 0);
        }
    }

#pragma unroll
    for (int dd = 0; dd < 4; ++dd)
#pragma unroll
        for (int c = 0; c < 2; ++c) {
            const size_t base = ((((size_t)(dq * 4 + dd) * 12 + rt) * 16 + (2 * w + c)) * 64 + l);
            ushort4 o;
            o.x = f2b(acc[dd][c][0]); o.y = f2b(acc[dd][c][1]);
            o.z = f2b(acc[dd][c][2]); o.w = f2b(acc[dd][c][3]);
            reinterpret_cast<ushort4*>(Vc)[base] = o;
        }
}

// Generic blocked-Horner scan: acc = V_top; acc = V_d + acc*Qk (nsteps).
// Grid (6 row-groups of 32, ngrp). 512 thr = 8 waves; Qk B-frags stationary in regs.
// Vin: C-frag blocks (bf16 or f32), indexed by LOCAL d. h0 replaces the top load
// when NAT != null and global group (grp_base+grp) == 127.
// Out: C-frag (bf16 or f32) at global group index, or fused epilogue to outF.
__global__ __launch_bounds__(512) void k_scan(const void* __restrict__ Vin, int in_bf16,
                                              const float* __restrict__ NAT, int grp_base,
                                              const float* __restrict__ ws, unsigned qb_off,
                                              int nsteps,
                                              void* __restrict__ OutC, int out_bf16,
                                              const float* __restrict__ xin,
                                              const float* __restrict__ W2,
                                              const float* __restrict__ b2p,
                                              float* __restrict__ outF) {
    __shared__ __align__(16) char smem[33856];
    short (*Sl)[2][8][64][8] = reinterpret_cast<short (*)[2][8][64][8]>(smem); // [buf][rt][ks][slot][j]
    float (*resl)[260]       = reinterpret_cast<float (*)[260]>(smem);          // overlays Sl (time-disjoint)
    float* w2l               = reinterpret_cast<float*>(smem + 33280);          // disjoint from Sl
    const int rt2 = blockIdx.x;            // 0..5
    const int grp = blockIdx.y;
    const int tid = threadIdx.x;
    const int w = tid >> 6, l = tid & 63;
    const ushort* Qb = reinterpret_cast<const ushort*>(ws + qb_off);

    s16x8 qreg[2][8];
#pragma unroll
    for (int c = 0; c < 2; ++c)
#pragma unroll
        for (int ks = 0; ks < 8; ++ks)
            qreg[c][ks] = *reinterpret_cast<const s16x8*>(Qb + (((2 * w + c) * 8 + ks) * 64 + l) * 8);

    f32x4 acc[2][2];
    int cur = 0;
    for (int it = 0; it < nsteps; ++it) {
        const int d = grp * nsteps + (nsteps - 1) - it;
        if (it == 0 && NAT != nullptr && (grp_base + grp) == 127) {
            // v_1023 = h0 = NATree[:, 1023, :]
#pragma unroll
            for (int rt = 0; rt < 2; ++rt)
#pragma unroll
                for (int c = 0; c < 2; ++c) {
                    const int col = w * 32 + c * 16 + (l & 15);
#pragma unroll
                    for (int r = 0; r < 4; ++r) {
                        const int n = rt2 * 32 + rt * 16 + (l >> 4) * 4 + r;
                        acc[rt][c][r] = NAT[((size_t)n * DD + (DD - 1)) * DM + col];
                    }
                }
        } else {
#pragma unroll
            for (int rt = 0; rt < 2; ++rt)
#pragma unroll
                for (int c = 0; c < 2; ++c) {
                    const size_t base = (((size_t)d * 12 + (rt2 * 2 + rt)) * 16 + (2 * w + c)) * 64 + l;
                    if (in_bf16) {
                        const ushort4 v = reinterpret_cast<const ushort4*>(Vin)[base];
                        acc[rt][c][0] = b2f(v.x); acc[rt][c][1] = b2f(v.y);
                        acc[rt][c][2] = b2f(v.z); acc[rt][c][3] = b2f(v.w);
                    } else {
                        acc[rt][c] = reinterpret_cast<const f32x4*>(Vin)[base];
                    }
                }
        }
        if (it > 0) {
#pragma unroll
            for (int ks = 0; ks < 8; ++ks) {
                const s16x8 a0 = *reinterpret_cast<const s16x8*>(&Sl[cur][0][ks][l][0]);
                const s16x8 a1 = *reinterpret_cast<const s16x8*>(&Sl[cur][1][ks][l][0]);
                acc[0][0] = __builtin_amdgcn_mfma_f32_16x16x32_bf16(a0, qreg[0][ks], acc[0][0], 0, 0, 0);
                acc[0][1] = __builtin_amdgcn_mfma_f32_16x16x32_bf16(a0, qreg[1][ks], acc[0][1], 0, 0, 0);
                acc[1][0] = __builtin_amdgcn_mfma_f32_16x16x32_bf16(a1, qreg[0][ks], acc[1][0], 0, 0, 0);
                acc[1][1] = __builtin_amdgcn_mfma_f32_16x16x32_bf16(a1, qreg[1][ks], acc[1][1], 0, 0, 0);
            }
        }
        if (it < nsteps - 1) {
            // acc -> Sl[cur^1] bf16 A-frag (wave writes its own ks = w)
#pragma unroll
            for (int rt = 0; rt < 2; ++rt)
#pragma unroll
                for (int c = 0; c < 2; ++c) {
                    const int col = w * 32 + c * 16 + (l & 15);
                    const int sl = 16 * ((col >> 3) & 3), jb = col & 7;
#pragma unroll
                    for (int r = 0; r < 4; ++r) {
                        const int row15 = (l >> 4) * 4 + r;
                        Sl[cur ^ 1][rt][w][row15 + sl][jb] = (short)f2b(acc[rt][c][r]);
                    }
                }
            __syncthreads();
            cur ^= 1;
        }
    }

    if (outF == nullptr) {
        const int gg = grp_base + grp;
#pragma unroll
        for (int rt = 0; rt < 2; ++rt)
#pragma unroll
            for (int c = 0; c < 2; ++c) {
                const size_t base = (((size_t)gg * 12 + (rt2 * 2 + rt)) * 16 + (2 * w + c)) * 64 + l;
                if (out_bf16) {
                    ushort4 o;
                    o.x = f2b(acc[rt][c][0]); o.y = f2b(acc[rt][c][1]);
                    o.z = f2b(acc[rt][c][2]); o.w = f2b(acc[rt][c][3]);
                    reinterpret_cast<ushort4*>(OutC)[base] = o;
                } else {
                    reinterpret_cast<f32x4*>(OutC)[base] = acc[rt][c];
                }
            }
    } else {
        // epilogue: res = relu(h + x); out = sigmoid(conv65(res) + b2)
        if (tid < DK) w2l[tid] = W2[tid];
        __syncthreads();   // all Sl reads done before resl overlays it
#pragma unroll
        for (int rt = 0; rt < 2; ++rt)
#pragma unroll
            for (int c = 0; c < 2; ++c) {
                const int col = w * 32 + c * 16 + (l & 15);
#pragma unroll
                for (int r = 0; r < 4; ++r) {
                    const int row = rt * 16 + (l >> 4) * 4 + r;
                    const int n = rt2 * 32 + row;
                    const float v = acc[rt][c][r] + xin[(size_t)n * DM + col];
                    resl[row][col] = v > 0.f ? v : 0.f;
                }
            }
        __syncthreads();
        const float b2v = *b2p;
        const int k = tid & 255;
        for (int rr = tid >> 8; rr < 32; rr += 2) {
            if (k < OUTW) {
                float o = b2v;
#pragma unroll
                for (int i = 0; i < DK; ++i) o += resl[rr][k + i] * w2l[i];
                outF[(size_t)(rt2 * 32 + rr) * OUTW + k] = sigm(o);
            }
        }
    }
}

// ======================= fp32 FALLBACK PATH (round-2, known-pass) =======================
#define OCB 16
#define ONB 64
#define OR1 24
#define ORB1 8
#define OPSTR 260
#define O_W0T 0u
#define O_W1T 65536u
#define O_PW  131072u
#define O_S   (131072u + 5u*65536u)

__global__ __launch_bounds__(256) void k_prep_o(const float* __restrict__ W, float* __restrict__ ws) {
    const int m = blockIdx.x, k = threadIdx.x;
    const float2 w = *reinterpret_cast<const float2*>(W + (size_t)k * 512 + m * 2);
    ws[O_W0T + m * 256 + k] = w.x;
    ws[O_W1T + m * 256 + k] = w.y;
}

__global__ __launch_bounds__(256) void k_sq_o(const float* __restrict__ A, float* __restrict__ C) {
    __shared__ float ar[4][OPSTR];
    const int r0 = blockIdx.x * 4, k = threadIdx.x;
    for (int r = 0; r < 4; ++r) ar[r][k] = A[(r0 + r) * 256 + k];
    __syncthreads();
    float a0 = 0.f, a1 = 0.f, a2 = 0.f, a3 = 0.f;
    for (int m = 0; m < 256; m += 4) {
        const float p0 = A[(m + 0) * 256 + k], p1 = A[(m + 1) * 256 + k];
        const float p2 = A[(m + 2) * 256 + k], p3 = A[(m + 3) * 256 + k];
        float4 t;
        t = *reinterpret_cast<const float4*>(&ar[0][m]); a0 += t.x * p0 + t.y * p1 + t.z * p2 + t.w * p3;
        t = *reinterpret_cast<const float4*>(&ar[1][m]); a1 += t.x * p0 + t.y * p1 + t.z * p2 + t.w * p3;
        t = *reinterpret_cast<const float4*>(&ar[2][m]); a2 += t.x * p0 + t.y * p1 + t.z * p2 + t.w * p3;
        t = *reinterpret_cast<const float4*>(&ar[3][m]); a3 += t.x * p0 + t.y * p1 + t.z * p2 + t.w * p3;
    }
    C[(r0 + 0) * 256 + k] = a0; C[(r0 + 1) * 256 + k] = a1;
    C[(r0 + 2) * 256 + k] = a2; C[(r0 + 3) * 256 + k] = a3;
}

__global__ __launch_bounds__(256) void k_phase1_o(const float* __restrict__ NAT,
                                                  const float* __restrict__ bvec,
                                                  const float* __restrict__ ws,
                                                  float* __restrict__ Sall) {
    __shared__ float Sl[OR1 * OPSTR];
    __shared__ float Rl[OR1 * OPSTR];
    const int rb = blockIdx.x, bb = blockIdx.y, tid = threadIdx.x;
    const int tj = tid & 63, ti = tid >> 6, n0 = rb * OR1;
    const float* __restrict__ W0t = ws + O_W0T;
    const float* __restrict__ W1t = ws + O_W1T;
    const float4 bv = *reinterpret_cast<const float4*>(bvec + 4 * tj);
    float acc[6][4];
    for (int it = 0; it < OCB; ++it) {
        const int d = bb * OCB + (OCB - 1) - it;
#pragma unroll
        for (int q = 0; q < 6; ++q) {
            const int row = q * 4 + ti;
            const float4 v = *reinterpret_cast<const float4*>(NAT + ((size_t)(n0 + row) * DD + d) * DM + 4 * tj);
            *reinterpret_cast<float4*>(&Rl[row * OPSTR + 4 * tj]) = v;
        }
        __syncthreads();
        if (d == DD - 1) {
#pragma unroll
            for (int r = 0; r < 6; ++r) {
                const float4 v = *reinterpret_cast<const float4*>(&Rl[(ti * 6 + r) * OPSTR + 4 * tj]);
                acc[r][0] = v.x; acc[r][1] = v.y; acc[r][2] = v.z; acc[r][3] = v.w;
            }
        } else {
#pragma unroll
            for (int r = 0; r < 6; ++r) {
                const float4 v = *reinterpret_cast<const float4*>(&Rl[(ti * 6 + r) * OPSTR + 4 * tj]);
                acc[r][0] = bv.x + sigm(v.x); acc[r][1] = bv.y + sigm(v.y);
                acc[r][2] = bv.z + sigm(v.z); acc[r][3] = bv.w + sigm(v.w);
            }
            if (it == 0) {
#pragma unroll 2
                for (int m = 0; m < DM; m += 2) {
                    const float4 w0a = *reinterpret_cast<const float4*>(W0t + m * DM + 4 * tj);
                    const float4 w0b = *reinterpret_cast<const float4*>(W0t + (m + 1) * DM + 4 * tj);
#pragma unroll
                    for (int r = 0; r < 6; ++r) {
                        const float2 rv = *reinterpret_cast<const float2*>(&Rl[(ti * 6 + r) * OPSTR + m]);
                        acc[r][0] += rv.x * w0a.x + rv.y * w0b.x;
                        acc[r][1] += rv.x * w0a.y + rv.y * w0b.y;
                        acc[r][2] += rv.x * w0a.z + rv.y * w0b.z;
                        acc[r][3] += rv.x * w0a.w + rv.y * w0b.w;
                    }
                }
            } else {
#pragma unroll 2
                for (int m = 0; m < DM; m += 2) {
                    const float4 w0a = *reinterpret_cast<const float4*>(W0t + m * DM + 4 * tj);
                    const float4 w0b = *reinterpret_cast<const float4*>(W0t + (m + 1) * DM + 4 * tj);
                    const float4 w1a = *reinterpret_cast<const float4*>(W1t + m * DM + 4 * tj);
                    const float4 w1b = *reinterpret_cast<const float4*>(W1t + (m + 1) * DM + 4 * tj);
#pragma unroll
                    for (int r = 0; r < 6; ++r) {
                        const float2 rv = *reinterpret_cast<const float2*>(&Rl[(ti * 6 + r) * OPSTR + m]);
                        const float2 sv = *reinterpret_cast<const float2*>(&Sl[(ti * 6 + r) * OPSTR + m]);
                        acc[r][0] += rv.x * w0a.x + rv.y * w0b.x + sv.x * w1a.x + sv.y * w1b.x;
                        acc[r][1] += rv.x * w0a.y + rv.y * w0b.y + sv.x * w1a.y + sv.y * w1b.y;
                        acc[r][2] += rv.x * w0a.z + rv.y * w0b.z + sv.x * w1a.z + sv.y * w1b.z;
                        acc[r][3] += rv.x * w0a.w + rv.y * w0b.w + sv.x * w1a.w + sv.y * w1b.w;
                    }
                }
            }
        }
        __syncthreads();
#pragma unroll
        for (int r = 0; r < 6; ++r) {
            float4 v; v.x = acc[r][0]; v.y = acc[r][1]; v.z = acc[r][2]; v.w = acc[r][3];
            *reinterpret_cast<float4*>(&Sl[(ti * 6 + r) * OPSTR + 4 * tj]) = v;
        }
        __syncthreads();
    }
    float* dst = Sall + ((size_t)bb * DN + n0) * DM;
#pragma unroll
    for (int r = 0; r < 6; ++r) {
        float4 v; v.x = acc[r][0]; v.y = acc[r][1]; v.z = acc[r][2]; v.w = acc[r][3];
        *reinterpret_cast<float4*>(dst + (size_t)(ti * 6 + r) * DM + 4 * tj) = v;
    }
}

__global__ __launch_bounds__(256) void k_phase2_o(const float* __restrict__ Sall,
                                                  const float* __restrict__ P,
                                                  const float* __restrict__ x,
                                                  const float* __restrict__ W2,
                                                  const float* __restrict__ b2p,
                                                  float* __restrict__ out) {
    __shared__ float Tl[2][DM];
    __shared__ float resl[DM];
    const int n = blockIdx.x, k = threadIdx.x;
    float a = Sall[((size_t)(ONB - 1) * DN + n) * DM + k];
    Tl[0][k] = a;
    __syncthreads();
    int cur = 0;
    for (int b = ONB - 2; b >= 0; --b) {
        const float s0 = Sall[((size_t)b * DN + n) * DM + k];
        float a0 = 0.f, a1 = 0.f, a2 = 0.f, a3 = 0.f;
        for (int m = 0; m < DM; m += 8) {
            const float4 t0 = *reinterpret_cast<const float4*>(&Tl[cur][m]);
            const float4 t1 = *reinterpret_cast<const float4*>(&Tl[cur][m + 4]);
            a0 += t0.x * P[(m + 0) * DM + k] + t1.x * P[(m + 4) * DM + k];
            a1 += t0.y * P[(m + 1) * DM + k] + t1.y * P[(m + 5) * DM + k];
            a2 += t0.z * P[(m + 2) * DM + k] + t1.z * P[(m + 6) * DM + k];
            a3 += t0.w * P[(m + 3) * DM + k] + t1.w * P[(m + 7) * DM + k];
        }
        a = s0 + ((a0 + a1) + (a2 + a3));
        Tl[cur ^ 1][k] = a;
        __syncthreads();
        cur ^= 1;
    }
    const float b2v = *b2p;
    float r = a + x[(size_t)n * DM + k];
    resl[k] = r > 0.f ? r : 0.f;
    __syncthreads();
    if (k < OUTW) {
        float o = b2v;
#pragma unroll 5
        for (int i = 0; i < DK; ++i) o += resl[k + i] * W2[i];
        out[(size_t)n * OUTW + k] = sigm(o);
    }
}

// ============================= launch =============================
extern "C" void kernel_launch(void* const* d_in, const int* in_sizes, int n_in,
                              void* d_out, int out_size, void* d_ws, size_t ws_size,
                              hipStream_t stream) {
    const float* NAT = (const float*)d_in[0];
    const float* W   = (const float*)d_in[1];
    const float* bv  = (const float*)d_in[2];
    const float* x   = (const float*)d_in[3];
    const float* W2  = (const float*)d_in[4];
    const float* b2  = (const float*)d_in[5];
    float* out = (float*)d_out;
    float* ws  = (float*)d_ws;

    if (ws_size >= TIER_B_BYTES) {
        // ---- MFMA path ----
        k_prep2<<<320, 256, 0, stream>>>(W, ws);
        k_sq256<<<256, 256, 0, stream>>>(ws + OFF_QF,  ws + OFF_A2,  nullptr);
        k_sq256<<<256, 256, 0, stream>>>(ws + OFF_A2,  ws + OFF_A4,  nullptr);
        k_sq256<<<256, 256, 0, stream>>>(ws + OFF_A4,  ws + OFF_A8,
                                         reinterpret_cast<ushort*>(ws + OFF_P8B));
        k_sq256<<<256, 256, 0, stream>>>(ws + OFF_A8,  ws + OFF_A16, nullptr);
        k_sq256<<<256, 256, 0, stream>>>(ws + OFF_A16, ws + OFF_A32, nullptr);
        k_sq256<<<256, 256, 0, stream>>>(ws + OFF_A32, ws + OFF_A64,
                                         reinterpret_cast<ushort*>(ws + OFF_P64B));

        unsigned short* Vc = reinterpret_cast<unsigned short*>(ws + OFF_VC);
        float* SA1 = ws + OFF_SA1;
        float* SA2 = ws + OFF_SA2;

        if (ws_size >= TIER_A_BYTES) {
            // tier A: full V materialization
            k_phase1a<<<dim3(12, 256), 512, 0, stream>>>(NAT, bv, ws, Vc, 0);
            k_scan<<<dim3(6, 128), 512, 0, stream>>>(Vc, 1, NAT, 0, ws, OFF_QB, 8,
                                                     SA1, 1, nullptr, nullptr, nullptr, nullptr);
        } else {
            // tier B: 8 chunks of 128 d-slices through one small V buffer
            for (int c = 0; c < 8; ++c) {
                k_phase1a<<<dim3(12, 32), 512, 0, stream>>>(NAT, bv, ws, Vc, c * 128);
                k_scan<<<dim3(6, 16), 512, 0, stream>>>(Vc, 1, NAT, c * 16, ws, OFF_QB, 8,
                                                        SA1, 1, nullptr, nullptr, nullptr, nullptr);
            }
        }
        // L2: combine 8 L1 groups per super-group with Q^8
        k_scan<<<dim3(6, 16), 512, 0, stream>>>(SA1, 1, nullptr, 0, ws, OFF_P8B, 8,
                                                SA2, 0, nullptr, nullptr, nullptr, nullptr);
        // L3: combine 16 super-groups with Q^64, fused epilogue
        k_scan<<<dim3(6, 1), 512, 0, stream>>>(SA2, 0, nullptr, 0, ws, OFF_P64B, 16,
                                               nullptr, 0, x, W2, b2, out);
    } else {
        // ---- fp32 fallback (round-2, known-pass) ----
        k_prep_o<<<256, 256, 0, stream>>>(W, ws);
        const float* q = ws + O_W1T;
        float* pw = ws + O_PW;
        k_sq_o<<<64, 256, 0, stream>>>(q,              pw + 0 * 65536);
        k_sq_o<<<64, 256, 0, stream>>>(pw + 0 * 65536, pw + 1 * 65536);
        k_sq_o<<<64, 256, 0, stream>>>(pw + 1 * 65536, pw + 2 * 65536);
        k_sq_o<<<64, 256, 0, stream>>>(pw + 2 * 65536, pw + 3 * 65536);
        float* Sall = ws + O_S;
        k_phase1_o<<<dim3(ORB1, ONB), 256, 0, stream>>>(NAT, bv, ws, Sall);
        k_phase2_o<<<192, 256, 0, stream>>>(Sall, pw + 3 * 65536, x, W2, b2, out);
    }
}